// Round 5
// baseline (60.399 us; speedup 1.0000x reference)
//
#include <hip/hip_runtime.h>

#define NB 8
#define NT 2048
#define NC 1024
#define NH 64

typedef __bf16 bf16x8 __attribute__((ext_vector_type(8)));
typedef float f32x4 __attribute__((ext_vector_type(4)));

static __device__ __forceinline__ float4 ldf4(const float* p) {
  return *reinterpret_cast<const float4*>(p);
}
static __device__ __forceinline__ unsigned pack_bf2(float a, float b) {
  unsigned short ua = __builtin_bit_cast(unsigned short, (__bf16)a);
  unsigned short ub = __builtin_bit_cast(unsigned short, (__bf16)b);
  return (unsigned)ua | ((unsigned)ub << 16);
}

// ---------------------------------------------------------------------------
// Kernel A: Wt[192][1024] bf16 = transpose+convert of Wq|Wk|Wv (fp32 [1024][64]).
// ---------------------------------------------------------------------------
__global__ __launch_bounds__(256) void wt_kernel(
    const float* __restrict__ Wq, const float* __restrict__ Wk,
    const float* __restrict__ Wv, __bf16* __restrict__ wt) {
  __shared__ __bf16 tl[64][72];
  const int tid = threadIdx.x;
  const int mat = blockIdx.x >> 4;
  const int k0 = (blockIdx.x & 15) * 64;
  const float* W = (mat == 0) ? Wq : (mat == 1) ? Wk : Wv;
#pragma unroll
  for (int it = 0; it < 4; ++it) {
    int f = tid + it * 256;
    int kk = f >> 4, c4 = (f & 15) * 4;
    float4 w = ldf4(&W[(k0 + kk) * NH + c4]);
    tl[c4 + 0][kk] = (__bf16)w.x;
    tl[c4 + 1][kk] = (__bf16)w.y;
    tl[c4 + 2][kk] = (__bf16)w.z;
    tl[c4 + 3][kk] = (__bf16)w.w;
  }
  __syncthreads();
#pragma unroll
  for (int it = 0; it < 2; ++it) {
    int f = tid + it * 256;
    int h = f >> 3, k8 = (f & 7) * 8;
    *reinterpret_cast<bf16x8*>(&wt[(mat * 64 + h) * NC + k0 + k8]) =
        *reinterpret_cast<const bf16x8*>(&tl[h][k8]);
  }
}

// ---------------------------------------------------------------------------
// Kernel B: q,k (bf16 row-major) and v^T (bf16 [b][h][t]) = x @ W via MFMA.
// BM=32, BN=192, BK=64. 512 blocks x 256 thr (4 waves) -> 2 blocks/CU so
// independent blocks overlap at barriers. Wave w: rows [0,32), cols w*48+[0,48).
// v epilogue goes through LDS transpose -> coalesced 16B stores.
// ---------------------------------------------------------------------------
__global__ __launch_bounds__(256, 2) void qkv_mfma_kernel(
    const float* __restrict__ x, const __bf16* __restrict__ wt,
    __bf16* __restrict__ qb, __bf16* __restrict__ kb, __bf16* __restrict__ vt) {
  __shared__ __bf16 As[32][72];    // [row][k]
  __shared__ __bf16 Bs[192][72];   // [col][k]
  __shared__ __bf16 vls[64][40];   // [h][t_local] for v transpose
  const int tid = threadIdx.x;
  const int lane = tid & 63;
  const int w = tid >> 6;          // 0..3
  const int row0 = blockIdx.x * 32;
  const int csub = w * 48;
  const int l15 = lane & 15, lg = lane >> 4;

  f32x4 acc[2][3];
#pragma unroll
  for (int i = 0; i < 2; ++i)
#pragma unroll
    for (int j = 0; j < 3; ++j) acc[i][j] = (f32x4){0.f, 0.f, 0.f, 0.f};

  float4 areg[2];
  bf16x8 breg[6];
  // prologue: prefetch chunk 0
#pragma unroll
  for (int it = 0; it < 2; ++it) {
    int f = tid + it * 256;
    int r = f >> 4, k4 = (f & 15) * 4;
    areg[it] = ldf4(&x[(row0 + r) * NC + k4]);
  }
#pragma unroll
  for (int it = 0; it < 6; ++it) {
    int f = tid + it * 256;
    int col = f >> 3, k8 = (f & 7) * 8;
    breg[it] = *reinterpret_cast<const bf16x8*>(&wt[col * NC + k8]);
  }

  for (int ch = 0; ch < 16; ++ch) {
    // write staged regs to LDS
#pragma unroll
    for (int it = 0; it < 2; ++it) {
      int f = tid + it * 256;
      int r = f >> 4, k4 = (f & 15) * 4;
      uint2 u = {pack_bf2(areg[it].x, areg[it].y), pack_bf2(areg[it].z, areg[it].w)};
      *reinterpret_cast<uint2*>(&As[r][k4]) = u;
    }
#pragma unroll
    for (int it = 0; it < 6; ++it) {
      int f = tid + it * 256;
      int col = f >> 3, k8 = (f & 7) * 8;
      *reinterpret_cast<bf16x8*>(&Bs[col][k8]) = breg[it];
    }
    __syncthreads();
    // prefetch chunk ch+1 (overlaps with MFMA below)
    if (ch < 15) {
      const int k0n = (ch + 1) * 64;
#pragma unroll
      for (int it = 0; it < 2; ++it) {
        int f = tid + it * 256;
        int r = f >> 4, k4 = (f & 15) * 4;
        areg[it] = ldf4(&x[(row0 + r) * NC + k0n + k4]);
      }
#pragma unroll
      for (int it = 0; it < 6; ++it) {
        int f = tid + it * 256;
        int col = f >> 3, k8 = (f & 7) * 8;
        breg[it] = *reinterpret_cast<const bf16x8*>(&wt[col * NC + k0n + k8]);
      }
    }
    // 2 MFMA k-steps over the staged BK=64
#pragma unroll
    for (int kk = 0; kk < 2; ++kk) {
      bf16x8 af[2], bfr[3];
#pragma unroll
      for (int rt = 0; rt < 2; ++rt)
        af[rt] = *reinterpret_cast<const bf16x8*>(&As[rt * 16 + l15][kk * 32 + lg * 8]);
#pragma unroll
      for (int nt = 0; nt < 3; ++nt)
        bfr[nt] = *reinterpret_cast<const bf16x8*>(&Bs[csub + nt * 16 + l15][kk * 32 + lg * 8]);
#pragma unroll
      for (int rt = 0; rt < 2; ++rt)
#pragma unroll
        for (int nt = 0; nt < 3; ++nt)
          acc[rt][nt] = __builtin_amdgcn_mfma_f32_16x16x32_bf16(af[rt], bfr[nt], acc[rt][nt], 0, 0, 0);
    }
    __syncthreads();
  }

  // epilogue: D layout col=l&15, row=(l>>4)*4+reg. mat uniform per (w,nt).
#pragma unroll
  for (int rt = 0; rt < 2; ++rt) {
#pragma unroll
    for (int nt = 0; nt < 3; ++nt) {
      int colbase = csub + nt * 16;   // wave-uniform, multiple of 16
      int mat = colbase >> 6;
      int h = (colbase & 63) + l15;
      if (mat == 0) {
#pragma unroll
        for (int r = 0; r < 4; ++r) {
          int row = row0 + rt * 16 + lg * 4 + r;
          qb[row * NH + h] = (__bf16)(acc[rt][nt][r] * 0.125f);  // pre-scale q
        }
      } else if (mat == 1) {
#pragma unroll
        for (int r = 0; r < 4; ++r) {
          int row = row0 + rt * 16 + lg * 4 + r;
          kb[row * NH + h] = (__bf16)acc[rt][nt][r];
        }
      } else {
        // v: stage transposed into LDS (4 consecutive t = one 8B write)
        ushort4 pk;
        pk.x = __builtin_bit_cast(unsigned short, (__bf16)acc[rt][nt][0]);
        pk.y = __builtin_bit_cast(unsigned short, (__bf16)acc[rt][nt][1]);
        pk.z = __builtin_bit_cast(unsigned short, (__bf16)acc[rt][nt][2]);
        pk.w = __builtin_bit_cast(unsigned short, (__bf16)acc[rt][nt][3]);
        *reinterpret_cast<ushort4*>(&vls[h][rt * 16 + lg * 4]) = pk;
      }
    }
  }
  __syncthreads();
  // cooperative coalesced v^T store: 64 h x 32 t, one 16B store per thread
  {
    int h = tid >> 2, t8 = (tid & 3) * 8;
    int bb = row0 >> 11;
    int t0l = row0 & (NT - 1);
    *reinterpret_cast<bf16x8*>(&vt[((size_t)bb * NH + h) * NT + t0l + t8]) =
        *reinterpret_cast<const bf16x8*>(&vls[h][t8]);
  }
}

// ---------------------------------------------------------------------------
// Kernel C: causal flash attention via MFMA, intra-block KV split.
// QBLK=16: grid dim3(128, 8) = 1024 blocks = 4 blocks/CU (16 waves/CU) for
// latency hiding. Co-resident blocks {id,id+256,id+512,id+768} share x and
// y-parity, so qt = (y%4<2) ? 127-x : x balances their summed work.
// 256 thr = 4 waves; wave w handles KV chunks c = w, w+4, ... (KVBLK=64).
// No global prefetch (VGPR tier); V frags loaded after QK^T (softmax hides).
// ---------------------------------------------------------------------------
__global__ __launch_bounds__(256, 4) void attn_mfma_kernel(
    const __bf16* __restrict__ qb, const __bf16* __restrict__ kb,
    const __bf16* __restrict__ vt, float* __restrict__ out) {
  __shared__ __bf16 ps[4][16][88];   // per-wave P tile [qrow][s], 176B rows
  __shared__ float obuf[4][16][68];  // per-wave O partial
  __shared__ float msh[4][16], lsh[4][16];
  const int tid = threadIdx.x;
  const int lane = tid & 63;
  const int w = tid >> 6;
  const int l15 = lane & 15, lg = lane >> 4;
  const int b = blockIdx.y;
  const int qt = ((blockIdx.y & 3) < 2) ? (127 - (int)blockIdx.x) : (int)blockIdx.x;
  const int q0 = qt * 16;
  const size_t bT = (size_t)b * NT;

  // Q fragments (pre-scaled by 1/8): B-operand of S^T = K·Q^T, col = l15
  bf16x8 qf[2];
#pragma unroll
  for (int kh = 0; kh < 2; ++kh)
    qf[kh] = *reinterpret_cast<const bf16x8*>(
        &qb[(bT + q0 + l15) * NH + kh * 32 + lg * 8]);

  float m = -1e30f, lsum = 0.f;
  f32x4 o[4];
#pragma unroll
  for (int j = 0; j < 4; ++j) o[j] = (f32x4){0.f, 0.f, 0.f, 0.f};

  const int nch = qt / 4 + 1;
  for (int c = w; c < nch; c += 4) {
    const int s0 = c * 64;
    // K fragments (A-operand): row = s, contiguous k octet per lane
    bf16x8 kf[4][2];
#pragma unroll
    for (int st = 0; st < 4; ++st)
#pragma unroll
      for (int kh = 0; kh < 2; ++kh)
        kf[st][kh] = *reinterpret_cast<const bf16x8*>(
            &kb[(bT + s0 + st * 16 + l15) * NH + kh * 32 + lg * 8]);
    // S^T[64 s][16 q]
    f32x4 s[4];
#pragma unroll
    for (int st = 0; st < 4; ++st) s[st] = (f32x4){0.f, 0.f, 0.f, 0.f};
    __builtin_amdgcn_s_setprio(1);
#pragma unroll
    for (int st = 0; st < 4; ++st)
#pragma unroll
      for (int kh = 0; kh < 2; ++kh)
        s[st] = __builtin_amdgcn_mfma_f32_16x16x32_bf16(kf[st][kh], qf[kh], s[st], 0, 0, 0);
    __builtin_amdgcn_s_setprio(0);

    // V fragments now: L2 latency hidden under softmax VALU below
    bf16x8 vf[4][2];
#pragma unroll
    for (int ht = 0; ht < 4; ++ht)
#pragma unroll
      for (int sh = 0; sh < 2; ++sh)
        vf[ht][sh] = *reinterpret_cast<const bf16x8*>(
            &vt[((size_t)b * NH + ht * 16 + l15) * NT + s0 + sh * 32 + lg * 8]);

    // causal mask on diagonal chunks. D: row(s)=st*16+lg*4+r, col(q)=l15.
    if (s0 + 63 > q0) {
      const int qg = q0 + l15;
#pragma unroll
      for (int st = 0; st < 4; ++st)
#pragma unroll
        for (int r = 0; r < 4; ++r) {
          int sg = s0 + st * 16 + lg * 4 + r;
          if (sg > qg) s[st][r] = -1e30f;
        }
    }
    // online softmax for q-row l15; reduce over lanes {l,l^16,l^32,l^48}
    float rmx = -1e30f;
#pragma unroll
    for (int st = 0; st < 4; ++st)
#pragma unroll
      for (int r = 0; r < 4; ++r) rmx = fmaxf(rmx, s[st][r]);
    rmx = fmaxf(rmx, __shfl_xor(rmx, 16));
    rmx = fmaxf(rmx, __shfl_xor(rmx, 32));
    float mn = fmaxf(m, rmx);
    float sc = __expf(m - mn);
    m = mn;
    float rs = 0.f;
#pragma unroll
    for (int st = 0; st < 4; ++st) {
      float p0 = __expf(s[st][0] - mn);
      float p1 = __expf(s[st][1] - mn);
      float p2 = __expf(s[st][2] - mn);
      float p3 = __expf(s[st][3] - mn);
      rs += (p0 + p1) + (p2 + p3);
      int sp = st * 16 + lg * 4;
      *reinterpret_cast<unsigned*>(&ps[w][l15][sp]) = pack_bf2(p0, p1);
      *reinterpret_cast<unsigned*>(&ps[w][l15][sp + 2]) = pack_bf2(p2, p3);
    }
    rs += __shfl_xor(rs, 16);
    rs += __shfl_xor(rs, 32);
    lsum = lsum * sc + rs;
    // rescale O: factor for q-row lg*4+r lives in lane lg*4+r
#pragma unroll
    for (int r = 0; r < 4; ++r) {
      float fsc = __shfl(sc, lg * 4 + r, 64);
#pragma unroll
      for (int ht = 0; ht < 4; ++ht) o[ht][r] *= fsc;
    }
    // PV: A = P (rows = q), B = V^T frags
    __builtin_amdgcn_s_setprio(1);
    bf16x8 pf[2];
#pragma unroll
    for (int sh = 0; sh < 2; ++sh)
      pf[sh] = *reinterpret_cast<const bf16x8*>(&ps[w][l15][sh * 32 + lg * 8]);
#pragma unroll
    for (int ht = 0; ht < 4; ++ht)
#pragma unroll
      for (int sh = 0; sh < 2; ++sh)
        o[ht] = __builtin_amdgcn_mfma_f32_16x16x32_bf16(pf[sh], vf[ht][sh], o[ht], 0, 0, 0);
    __builtin_amdgcn_s_setprio(0);
  }

  // publish partials
  if (lg == 0) {
    msh[w][l15] = m;
    lsh[w][l15] = lsum;
  }
#pragma unroll
  for (int ht = 0; ht < 4; ++ht)
#pragma unroll
    for (int r = 0; r < 4; ++r)
      obuf[w][lg * 4 + r][ht * 16 + l15] = o[ht][r];
  __syncthreads();

  // combine the 4 wave-partials; write fp32 out (float4 per thread)
  {
    int qr = tid >> 4, h4 = (tid & 15) * 4;
    float m0 = msh[0][qr], m1 = msh[1][qr], m2 = msh[2][qr], m3 = msh[3][qr];
    float M = fmaxf(fmaxf(m0, m1), fmaxf(m2, m3));
    float e0 = __expf(m0 - M), e1 = __expf(m1 - M);
    float e2 = __expf(m2 - M), e3 = __expf(m3 - M);
    float L = e0 * lsh[0][qr] + e1 * lsh[1][qr] + e2 * lsh[2][qr] + e3 * lsh[3][qr];
    float inv = 1.f / L;
    float4 res;
    float* rp = &res.x;
#pragma unroll
    for (int i = 0; i < 4; ++i) {
      int h = h4 + i;
      float v = e0 * obuf[0][qr][h] + e1 * obuf[1][qr][h] +
                e2 * obuf[2][qr][h] + e3 * obuf[3][qr][h];
      rp[i] = v * inv;
    }
    *reinterpret_cast<float4*>(&out[(bT + q0 + qr) * NH + h4]) = res;
  }
}

extern "C" void kernel_launch(void* const* d_in, const int* in_sizes, int n_in,
                              void* d_out, int out_size, void* d_ws, size_t ws_size,
                              hipStream_t stream) {
  const float* x  = (const float*)d_in[0];
  const float* Wq = (const float*)d_in[1];
  const float* Wk = (const float*)d_in[2];
  const float* Wv = (const float*)d_in[3];
  float* out = (float*)d_out;

  char* ws = (char*)d_ws;
  __bf16* wt = (__bf16*)(ws);                        // 192*1024*2 = 384 KB
  __bf16* qb = (__bf16*)(ws + 393216);               // 2 MB
  __bf16* kb = (__bf16*)(ws + 393216 + 2097152);     // 2 MB
  __bf16* vt = (__bf16*)(ws + 393216 + 2 * 2097152); // 2 MB  (total ~6.7 MB)

  wt_kernel<<<dim3(48), dim3(256), 0, stream>>>(Wq, Wk, Wv, wt);
  qkv_mfma_kernel<<<dim3(512), dim3(256), 0, stream>>>(x, wt, qb, kb, vt);
  attn_mfma_kernel<<<dim3(128, 8), dim3(256), 0, stream>>>(qb, kb, vt, out);
}

// Round 6
// 52.644 us; speedup vs baseline: 1.1473x; 1.1473x over previous
//
#include <hip/hip_runtime.h>

#define NB 8
#define NT 2048
#define NC 1024
#define NH 64

typedef __bf16 bf16x8 __attribute__((ext_vector_type(8)));
typedef float f32x4 __attribute__((ext_vector_type(4)));

static __device__ __forceinline__ float4 ldf4(const float* p) {
  return *reinterpret_cast<const float4*>(p);
}
static __device__ __forceinline__ unsigned pack_bf2(float a, float b) {
  unsigned short ua = __builtin_bit_cast(unsigned short, (__bf16)a);
  unsigned short ub = __builtin_bit_cast(unsigned short, (__bf16)b);
  return (unsigned)ua | ((unsigned)ub << 16);
}
// async global->LDS DMA, 16B per lane; LDS dest must be wave-uniform-base + lane*16
static __device__ __forceinline__ void gload16(const __bf16* g, __bf16* l) {
  __builtin_amdgcn_global_load_lds(
      (const __attribute__((address_space(1))) unsigned int*)g,
      (__attribute__((address_space(3))) unsigned int*)l, 16, 0, 0);
}

// ---------------------------------------------------------------------------
// Kernel A: Wt[192][1024] bf16 = transpose+convert of Wq|Wk|Wv (fp32 [1024][64]).
// ---------------------------------------------------------------------------
__global__ __launch_bounds__(256) void wt_kernel(
    const float* __restrict__ Wq, const float* __restrict__ Wk,
    const float* __restrict__ Wv, __bf16* __restrict__ wt) {
  __shared__ __bf16 tl[64][72];
  const int tid = threadIdx.x;
  const int mat = blockIdx.x >> 4;
  const int k0 = (blockIdx.x & 15) * 64;
  const float* W = (mat == 0) ? Wq : (mat == 1) ? Wk : Wv;
#pragma unroll
  for (int it = 0; it < 4; ++it) {
    int f = tid + it * 256;
    int kk = f >> 4, c4 = (f & 15) * 4;
    float4 w = ldf4(&W[(k0 + kk) * NH + c4]);
    tl[c4 + 0][kk] = (__bf16)w.x;
    tl[c4 + 1][kk] = (__bf16)w.y;
    tl[c4 + 2][kk] = (__bf16)w.z;
    tl[c4 + 3][kk] = (__bf16)w.w;
  }
  __syncthreads();
#pragma unroll
  for (int it = 0; it < 2; ++it) {
    int f = tid + it * 256;
    int h = f >> 3, k8 = (f & 7) * 8;
    *reinterpret_cast<bf16x8*>(&wt[(mat * 64 + h) * NC + k0 + k8]) =
        *reinterpret_cast<const bf16x8*>(&tl[h][k8]);
  }
}

// ---------------------------------------------------------------------------
// Kernel B: q,k (bf16 row-major) and v^T (bf16 [b][h][t]) = x @ W via MFMA.
// BM=32, BN=192, BK=64. 512 blocks x 256 thr (4 waves), 2 blocks/CU.
// B-tile staged via global_load_lds (16B DMA) into unpadded double-buffered
// Bs[2][192][64]; bank conflicts fixed by XOR-octet swizzle applied on BOTH
// the global source address and the ds_read address (involution, rule 21).
// A-tile reg-staged (fp32->bf16 pack). One barrier per chunk.
// ---------------------------------------------------------------------------
__global__ __launch_bounds__(256, 2) void qkv_mfma_kernel(
    const float* __restrict__ x, const __bf16* __restrict__ wt,
    __bf16* __restrict__ qb, __bf16* __restrict__ kb, __bf16* __restrict__ vt) {
  __shared__ __bf16 As[2][32][72];   // [buf][row][k]
  __shared__ __bf16 Bs[2][192][64];  // [buf][col][k], unpadded (DMA dest linear)
  __shared__ __bf16 vls[64][40];     // [h][t_local] for v transpose
  const int tid = threadIdx.x;
  const int lane = tid & 63;
  const int w = tid >> 6;          // 0..3
  const int row0 = blockIdx.x * 32;
  const int csub = w * 48;
  const int l15 = lane & 15, lg = lane >> 4;

  f32x4 acc[2][3];
#pragma unroll
  for (int i = 0; i < 2; ++i)
#pragma unroll
    for (int j = 0; j < 3; ++j) acc[i][j] = (f32x4){0.f, 0.f, 0.f, 0.f};

  float4 areg[2];
  // prologue: A(0) -> regs, B(0) -> Bs[0] via DMA (pre-swizzled source octet)
#pragma unroll
  for (int it = 0; it < 2; ++it) {
    int f = tid + it * 256;
    int r = f >> 4, k4 = (f & 15) * 4;
    areg[it] = ldf4(&x[(row0 + r) * NC + k4]);
  }
#pragma unroll
  for (int it = 0; it < 6; ++it) {
    int f = tid + it * 256;
    int col = f >> 3, oct = f & 7;
    gload16(&wt[col * NC + ((oct ^ (col & 7)) * 8)], &Bs[0][0][0] + f * 8);
  }

  for (int ch = 0; ch < 16; ++ch) {
    const int cur = ch & 1;
    // (a) pack A regs into As[cur]
#pragma unroll
    for (int it = 0; it < 2; ++it) {
      int f = tid + it * 256;
      int r = f >> 4, k4 = (f & 15) * 4;
      uint2 u = {pack_bf2(areg[it].x, areg[it].y), pack_bf2(areg[it].z, areg[it].w)};
      *reinterpret_cast<uint2*>(&As[cur][r][k4]) = u;
    }
    // (b) barrier: drains Bs[cur] DMA (vmcnt0) + publishes As[cur];
    //     also guarantees everyone finished reading buffers [1-cur]
    __syncthreads();
    // (c) issue next chunk: B DMA -> Bs[1-cur], A -> regs (overlaps MFMA)
    if (ch < 15) {
      const int k0n = (ch + 1) * 64;
      __bf16* bdst = &Bs[1 - cur][0][0];
#pragma unroll
      for (int it = 0; it < 6; ++it) {
        int f = tid + it * 256;
        int col = f >> 3, oct = f & 7;
        gload16(&wt[col * NC + k0n + ((oct ^ (col & 7)) * 8)], bdst + f * 8);
      }
#pragma unroll
      for (int it = 0; it < 2; ++it) {
        int f = tid + it * 256;
        int r = f >> 4, k4 = (f & 15) * 4;
        areg[it] = ldf4(&x[(row0 + r) * NC + k0n + k4]);
      }
    }
    // (d) 2 MFMA k-steps; B read address applies the same XOR swizzle
#pragma unroll
    for (int kk = 0; kk < 2; ++kk) {
      bf16x8 af[2], bfr[3];
#pragma unroll
      for (int rt = 0; rt < 2; ++rt)
        af[rt] = *reinterpret_cast<const bf16x8*>(&As[cur][rt * 16 + l15][kk * 32 + lg * 8]);
#pragma unroll
      for (int nt = 0; nt < 3; ++nt) {
        int col = csub + nt * 16 + l15;
        int oct = (kk * 4 + lg) ^ (col & 7);
        bfr[nt] = *reinterpret_cast<const bf16x8*>(&Bs[cur][col][oct * 8]);
      }
#pragma unroll
      for (int rt = 0; rt < 2; ++rt)
#pragma unroll
        for (int nt = 0; nt < 3; ++nt)
          acc[rt][nt] = __builtin_amdgcn_mfma_f32_16x16x32_bf16(af[rt], bfr[nt], acc[rt][nt], 0, 0, 0);
    }
    // no trailing barrier: next iteration's (b) separates all hazards
  }

  // epilogue: D layout col=l&15, row=(l>>4)*4+reg. mat uniform per (w,nt).
#pragma unroll
  for (int rt = 0; rt < 2; ++rt) {
#pragma unroll
    for (int nt = 0; nt < 3; ++nt) {
      int colbase = csub + nt * 16;   // wave-uniform, multiple of 16
      int mat = colbase >> 6;
      int h = (colbase & 63) + l15;
      if (mat == 0) {
#pragma unroll
        for (int r = 0; r < 4; ++r) {
          int row = row0 + rt * 16 + lg * 4 + r;
          qb[row * NH + h] = (__bf16)(acc[rt][nt][r] * 0.125f);  // pre-scale q
        }
      } else if (mat == 1) {
#pragma unroll
        for (int r = 0; r < 4; ++r) {
          int row = row0 + rt * 16 + lg * 4 + r;
          kb[row * NH + h] = (__bf16)acc[rt][nt][r];
        }
      } else {
        // v: stage transposed into LDS (4 consecutive t = one 8B write)
        ushort4 pk;
        pk.x = __builtin_bit_cast(unsigned short, (__bf16)acc[rt][nt][0]);
        pk.y = __builtin_bit_cast(unsigned short, (__bf16)acc[rt][nt][1]);
        pk.z = __builtin_bit_cast(unsigned short, (__bf16)acc[rt][nt][2]);
        pk.w = __builtin_bit_cast(unsigned short, (__bf16)acc[rt][nt][3]);
        *reinterpret_cast<ushort4*>(&vls[h][rt * 16 + lg * 4]) = pk;
      }
    }
  }
  __syncthreads();
  // cooperative coalesced v^T store: 64 h x 32 t, one 16B store per thread
  {
    int h = tid >> 2, t8 = (tid & 3) * 8;
    int bb = row0 >> 11;
    int t0l = row0 & (NT - 1);
    *reinterpret_cast<bf16x8*>(&vt[((size_t)bb * NH + h) * NT + t0l + t8]) =
        *reinterpret_cast<const bf16x8*>(&vls[h][t8]);
  }
}

// ---------------------------------------------------------------------------
// Kernel C: causal flash attention via MFMA, intra-block KV split.
// (exact R4 version, 48.1 us config) Grid dim3(64,8); qt = (y<4) ? 63-x : x
// so the two blocks sharing a CU have complementary work. 256 thr = 4 waves;
// wave w handles KV chunks c = w, w+4, ... setprio(1) around MFMA clusters.
// ---------------------------------------------------------------------------
__global__ __launch_bounds__(256, 2) void attn_mfma_kernel(
    const __bf16* __restrict__ qb, const __bf16* __restrict__ kb,
    const __bf16* __restrict__ vt, float* __restrict__ out) {
  __shared__ __bf16 ps[4][32][72];   // per-wave P tile [qrow][s]
  __shared__ float obuf[4][32][68];  // per-wave O partial
  __shared__ float msh[4][32], lsh[4][32];
  const int tid = threadIdx.x;
  const int lane = tid & 63;
  const int w = tid >> 6;
  const int l15 = lane & 15, lg = lane >> 4;
  const int b = blockIdx.y;
  const int qt = (blockIdx.y < 4) ? (63 - (int)blockIdx.x) : (int)blockIdx.x;
  const int q0 = qt * 32;
  const size_t bT = (size_t)b * NT;

  bf16x8 qf[2][2];
#pragma unroll
  for (int ct = 0; ct < 2; ++ct)
#pragma unroll
    for (int kh = 0; kh < 2; ++kh)
      qf[ct][kh] = *reinterpret_cast<const bf16x8*>(
          &qb[(bT + q0 + ct * 16 + l15) * NH + kh * 32 + lg * 8]);

  float m[2] = {-1e30f, -1e30f};
  float lsum[2] = {0.f, 0.f};
  f32x4 o[2][4];
#pragma unroll
  for (int i = 0; i < 2; ++i)
#pragma unroll
    for (int j = 0; j < 4; ++j) o[i][j] = (f32x4){0.f, 0.f, 0.f, 0.f};

  const int nch = qt / 2 + 1;
  bf16x8 kf[4][2], vf[4][2];
  if (w < nch) {
    const int s0 = w * 64;
#pragma unroll
    for (int st = 0; st < 4; ++st)
#pragma unroll
      for (int kh = 0; kh < 2; ++kh)
        kf[st][kh] = *reinterpret_cast<const bf16x8*>(
            &kb[(bT + s0 + st * 16 + l15) * NH + kh * 32 + lg * 8]);
#pragma unroll
    for (int ht = 0; ht < 4; ++ht)
#pragma unroll
      for (int sh = 0; sh < 2; ++sh)
        vf[ht][sh] = *reinterpret_cast<const bf16x8*>(
            &vt[((size_t)b * NH + ht * 16 + l15) * NT + s0 + sh * 32 + lg * 8]);
  }

  for (int c = w; c < nch; c += 4) {
    const int s0 = c * 64;
    f32x4 s[4][2];
#pragma unroll
    for (int st = 0; st < 4; ++st)
#pragma unroll
      for (int ct = 0; ct < 2; ++ct) s[st][ct] = (f32x4){0.f, 0.f, 0.f, 0.f};
    __builtin_amdgcn_s_setprio(1);
#pragma unroll
    for (int st = 0; st < 4; ++st)
#pragma unroll
      for (int ct = 0; ct < 2; ++ct)
#pragma unroll
        for (int kh = 0; kh < 2; ++kh)
          s[st][ct] = __builtin_amdgcn_mfma_f32_16x16x32_bf16(kf[st][kh], qf[ct][kh], s[st][ct], 0, 0, 0);
    __builtin_amdgcn_s_setprio(0);

    const int cn = c + 4;
    bf16x8 kfn[4][2], vfn[4][2];
    if (cn < nch) {
      const int sn = cn * 64;
#pragma unroll
      for (int st = 0; st < 4; ++st)
#pragma unroll
        for (int kh = 0; kh < 2; ++kh)
          kfn[st][kh] = *reinterpret_cast<const bf16x8*>(
              &kb[(bT + sn + st * 16 + l15) * NH + kh * 32 + lg * 8]);
#pragma unroll
      for (int ht = 0; ht < 4; ++ht)
#pragma unroll
        for (int sh = 0; sh < 2; ++sh)
          vfn[ht][sh] = *reinterpret_cast<const bf16x8*>(
              &vt[((size_t)b * NH + ht * 16 + l15) * NT + sn + sh * 32 + lg * 8]);
    }

    if (s0 + 63 > q0) {
#pragma unroll
      for (int st = 0; st < 4; ++st)
#pragma unroll
        for (int ct = 0; ct < 2; ++ct) {
          int qg = q0 + ct * 16 + l15;
#pragma unroll
          for (int r = 0; r < 4; ++r) {
            int sg = s0 + st * 16 + lg * 4 + r;
            if (sg > qg) s[st][ct][r] = -1e30f;
          }
        }
    }
    float scv[2];
#pragma unroll
    for (int ct = 0; ct < 2; ++ct) {
      float rmx = -1e30f;
#pragma unroll
      for (int st = 0; st < 4; ++st)
#pragma unroll
        for (int r = 0; r < 4; ++r) rmx = fmaxf(rmx, s[st][ct][r]);
      rmx = fmaxf(rmx, __shfl_xor(rmx, 16));
      rmx = fmaxf(rmx, __shfl_xor(rmx, 32));
      float mn = fmaxf(m[ct], rmx);
      float sc = __expf(m[ct] - mn);
      m[ct] = mn;
      float rs = 0.f;
#pragma unroll
      for (int st = 0; st < 4; ++st) {
        float p0 = __expf(s[st][ct][0] - mn);
        float p1 = __expf(s[st][ct][1] - mn);
        float p2 = __expf(s[st][ct][2] - mn);
        float p3 = __expf(s[st][ct][3] - mn);
        rs += (p0 + p1) + (p2 + p3);
        int sp = st * 16 + lg * 4;
        *reinterpret_cast<unsigned*>(&ps[w][ct * 16 + l15][sp]) = pack_bf2(p0, p1);
        *reinterpret_cast<unsigned*>(&ps[w][ct * 16 + l15][sp + 2]) = pack_bf2(p2, p3);
      }
      rs += __shfl_xor(rs, 16);
      rs += __shfl_xor(rs, 32);
      lsum[ct] = lsum[ct] * sc + rs;
      scv[ct] = sc;
    }
#pragma unroll
    for (int rt = 0; rt < 2; ++rt)
#pragma unroll
      for (int r = 0; r < 4; ++r) {
        float fsc = __shfl(scv[rt], lg * 4 + r, 64);
#pragma unroll
        for (int ht = 0; ht < 4; ++ht) o[rt][ht][r] *= fsc;
      }
    __builtin_amdgcn_s_setprio(1);
#pragma unroll
    for (int rt = 0; rt < 2; ++rt) {
      bf16x8 pf[2];
#pragma unroll
      for (int sh = 0; sh < 2; ++sh)
        pf[sh] = *reinterpret_cast<const bf16x8*>(&ps[w][rt * 16 + l15][sh * 32 + lg * 8]);
#pragma unroll
      for (int ht = 0; ht < 4; ++ht)
#pragma unroll
        for (int sh = 0; sh < 2; ++sh)
          o[rt][ht] = __builtin_amdgcn_mfma_f32_16x16x32_bf16(pf[sh], vf[ht][sh], o[rt][ht], 0, 0, 0);
    }
    __builtin_amdgcn_s_setprio(0);
    if (cn < nch) {
#pragma unroll
      for (int st = 0; st < 4; ++st)
#pragma unroll
        for (int kh = 0; kh < 2; ++kh) kf[st][kh] = kfn[st][kh];
#pragma unroll
      for (int ht = 0; ht < 4; ++ht)
#pragma unroll
        for (int sh = 0; sh < 2; ++sh) vf[ht][sh] = vfn[ht][sh];
    }
  }

  if (lg == 0) {
#pragma unroll
    for (int ct = 0; ct < 2; ++ct) {
      msh[w][ct * 16 + l15] = m[ct];
      lsh[w][ct * 16 + l15] = lsum[ct];
    }
  }
#pragma unroll
  for (int rt = 0; rt < 2; ++rt)
#pragma unroll
    for (int ht = 0; ht < 4; ++ht)
#pragma unroll
      for (int r = 0; r < 4; ++r)
        obuf[w][rt * 16 + lg * 4 + r][ht * 16 + l15] = o[rt][ht][r];
  __syncthreads();

  {
    int qr = tid >> 3, h8 = (tid & 7) * 8;
    float m0 = msh[0][qr], m1 = msh[1][qr], m2 = msh[2][qr], m3 = msh[3][qr];
    float M = fmaxf(fmaxf(m0, m1), fmaxf(m2, m3));
    float e0 = __expf(m0 - M), e1 = __expf(m1 - M);
    float e2 = __expf(m2 - M), e3 = __expf(m3 - M);
    float L = e0 * lsh[0][qr] + e1 * lsh[1][qr] + e2 * lsh[2][qr] + e3 * lsh[3][qr];
    float inv = 1.f / L;
#pragma unroll
    for (int i = 0; i < 8; ++i) {
      int h = h8 + i;
      float v = e0 * obuf[0][qr][h] + e1 * obuf[1][qr][h] +
                e2 * obuf[2][qr][h] + e3 * obuf[3][qr][h];
      out[(bT + q0 + qr) * NH + h] = v * inv;
    }
  }
}

extern "C" void kernel_launch(void* const* d_in, const int* in_sizes, int n_in,
                              void* d_out, int out_size, void* d_ws, size_t ws_size,
                              hipStream_t stream) {
  const float* x  = (const float*)d_in[0];
  const float* Wq = (const float*)d_in[1];
  const float* Wk = (const float*)d_in[2];
  const float* Wv = (const float*)d_in[3];
  float* out = (float*)d_out;

  char* ws = (char*)d_ws;
  __bf16* wt = (__bf16*)(ws);                        // 192*1024*2 = 384 KB
  __bf16* qb = (__bf16*)(ws + 393216);               // 2 MB
  __bf16* kb = (__bf16*)(ws + 393216 + 2097152);     // 2 MB
  __bf16* vt = (__bf16*)(ws + 393216 + 2 * 2097152); // 2 MB  (total ~6.7 MB)

  wt_kernel<<<dim3(48), dim3(256), 0, stream>>>(Wq, Wk, Wv, wt);
  qkv_mfma_kernel<<<dim3(512), dim3(256), 0, stream>>>(x, wt, qb, kb, vt);
  attn_mfma_kernel<<<dim3(64, 8), dim3(256), 0, stream>>>(qb, kb, vt, out);
}